// Round 4
// baseline (124.841 us; speedup 1.0000x reference)
//
#include <hip/hip_runtime.h>
#include <hip/hip_bf16.h>
#include <stdint.h>

#define HIDDEN 1024
#define NHEAD  16
#define HS     64
#define BATCH  2
#define SEQ    2048
#define MTOT   (BATCH*SEQ)
#define NQKV   (3*HIDDEN)

typedef __hip_bfloat16 bf16;
typedef __attribute__((ext_vector_type(8))) short s16x8;
typedef __attribute__((ext_vector_type(4))) float f32x4;
typedef __attribute__((ext_vector_type(16))) float f32x16;

__device__ __forceinline__ short f2bf(float f) {
  bf16 h = __float2bfloat16(f);
  return *reinterpret_cast<short*>(&h);
}

__device__ __forceinline__ unsigned cvt_pk_bf16(float lo, float hi) {
  unsigned r;
  asm("v_cvt_pk_bf16_f32 %0, %1, %2" : "=v"(r) : "v"(lo), "v"(hi));
  return r;
}

// LDS chunk-swizzle, 8 chunks (16B each) per row: chunk blk lives at blk^(row&7).
__device__ __forceinline__ int swz(int row, int blk) {
  return (row*8 + (blk ^ (row & 7)))*8;
}

#define GLOAD_LDS(gp, lp) \
  __builtin_amdgcn_global_load_lds((const __attribute__((address_space(1))) void*)(gp), \
                                   (__attribute__((address_space(3))) void*)(lp), 16, 0, 0)

// bijective XCD-chunk swizzle; requires nwg % 8 == 0 (true for all our grids)
__device__ __forceinline__ int xcd_swz(int orig, int nwg) {
  return (orig & 7)*(nwg >> 3) + (orig >> 3);
}

// ---------------- convert x (fp32 -> bf16), 8 elems/thread ----------------
__global__ void k_cvt_x(const float* __restrict__ x, short* __restrict__ xb, int n8) {
  int i = blockIdx.x*256 + threadIdx.x;
  if (i >= n8) return;
  const f32x4* xv = (const f32x4*)x;
  f32x4 a = xv[2*i], b = xv[2*i+1];
  s16x8 o = { f2bf(a[0]), f2bf(a[1]), f2bf(a[2]), f2bf(a[3]),
              f2bf(b[0]), f2bf(b[1]), f2bf(b[2]), f2bf(b[3]) };
  *(s16x8*)&xb[i*8] = o;
}

// ------------- transpose-convert W[K][N] fp32 -> WT[N][K] bf16 -------------
__global__ void k_cvt_wT(const float* __restrict__ W, bf16* __restrict__ WT, int K, int N) {
  __shared__ __align__(16) float tile[64][65];
  int n0 = blockIdx.x*64, k0 = blockIdx.y*64;
  int t = threadIdx.x;
  #pragma unroll
  for (int c = 0; c < 4; c++) {
    int s = c*256 + t;
    int r = s >> 4;
    int cc = s & 15;
    f32x4 v = *(const f32x4*)&W[(size_t)(k0 + r)*N + n0 + cc*4];
    tile[r][cc*4+0] = v[0]; tile[r][cc*4+1] = v[1];
    tile[r][cc*4+2] = v[2]; tile[r][cc*4+3] = v[3];
  }
  __syncthreads();
  #pragma unroll
  for (int c = 0; c < 2; c++) {
    int s = c*256 + t;
    int r = s >> 3;
    int cc = s & 7;
    s16x8 o;
    #pragma unroll
    for (int u = 0; u < 8; u++) o[u] = f2bf(tile[cc*8+u][r]);
    *(s16x8*)&WT[(size_t)(n0 + r)*K + k0 + cc*8] = o;
  }
}

// -------- GEMM: C[M][N] = A[M][K](bf16) * BT[N][K]^T(bf16) + bias --------
template<int OUT_BF16>
__global__ __launch_bounds__(256) void k_gemm(
    const bf16* __restrict__ A, const bf16* __restrict__ BT,
    const float* __restrict__ bias, void* __restrict__ Cout,
    int M, int N, int K)
{
  __shared__ __align__(16) short Asl[128*64];
  __shared__ __align__(16) short Bsl[128*64];
  int t = threadIdx.x;
  int lane = t & 63, w = t >> 6;
  int q = lane & 15, g = lane >> 4;
  int nwg = gridDim.x*gridDim.y;
  int swzid = xcd_swz(blockIdx.y*gridDim.x + blockIdx.x, nwg);
  int bx = swzid % gridDim.x, by = swzid / gridDim.x;
  int row0 = by*128, col0 = bx*128;
  int wr = (w >> 1)*64, wc = (w & 1)*64;

  f32x4 acc[4][4] = {};

  for (int kt = 0; kt < K; kt += 64) {
    __syncthreads();
    #pragma unroll
    for (int c = 0; c < 4; c++) {
      int s = c*256 + t, r = s >> 3, bd = s & 7, bs = bd ^ (r & 7);
      GLOAD_LDS(&A[(size_t)(row0 + r)*K + kt + bs*8], &Asl[s*8]);
      GLOAD_LDS(&BT[(size_t)(col0 + r)*K + kt + bs*8], &Bsl[s*8]);
    }
    __syncthreads();
    #pragma unroll
    for (int kk = 0; kk < 2; kk++) {
      s16x8 af[4], bfr[4];
      #pragma unroll
      for (int i = 0; i < 4; i++) {
        af[i]  = *(const s16x8*)&Asl[swz(wr + i*16 + q, kk*4 + g)];
        bfr[i] = *(const s16x8*)&Bsl[swz(wc + i*16 + q, kk*4 + g)];
      }
      __builtin_amdgcn_s_setprio(1);
      #pragma unroll
      for (int i = 0; i < 4; i++)
        #pragma unroll
        for (int j = 0; j < 4; j++)
          acc[i][j] = __builtin_amdgcn_mfma_f32_16x16x32_bf16(af[i], bfr[j], acc[i][j], 0, 0, 0);
      __builtin_amdgcn_s_setprio(0);
    }
  }
  #pragma unroll
  for (int i = 0; i < 4; i++) {
    #pragma unroll
    for (int j = 0; j < 4; j++) {
      int col = col0 + wc + j*16 + q;
      float bv = bias[col];
      int rowb = row0 + wr + i*16 + g*4;
      #pragma unroll
      for (int r = 0; r < 4; r++) {
        float v = acc[i][j][r] + bv;
        if (OUT_BF16)
          ((bf16*)Cout)[(size_t)(rowb + r)*N + col] = __float2bfloat16(v);
        else
          ((float*)Cout)[(size_t)(rowb + r)*N + col] = v;
      }
    }
  }
}

// ------- repack V with PV key-permutation baked into column order -------
// For 32x32x16 swapped-QK^T: S^T reg r of lane (q,hi) holds key
// a = (r&3)+8*(r>>2)+4*hi; PV A-frag slot needs pos = (r>>3)*16+hi*8+(r&7).
// a = pos with bits 2<->3 swapped. So Vt[.][s0+p] = V[s0 + bitswap23(p)][.].
__global__ void k_repack_v(const bf16* __restrict__ qkv, bf16* __restrict__ Vt) {
  int s0 = blockIdx.x*64;
  int bh = blockIdx.y;
  int b = bh >> 4, h = bh & 15;
  __shared__ __align__(16) short vt[64][68];
  int t = threadIdx.x;
  #pragma unroll
  for (int c = 0; c < 2; c++) {
    int s = c*256 + t, r = s >> 3, bd = s & 7;
    s16x8 v = *(const s16x8*)&qkv[(size_t)(b*SEQ + s0 + r)*NQKV + 2*HIDDEN + h*HS + bd*8];
    #pragma unroll
    for (int u = 0; u < 8; u++) vt[r][bd*8+u] = v[u];
  }
  __syncthreads();
  #pragma unroll
  for (int c = 0; c < 2; c++) {
    int s = c*256 + t, d = s >> 3, bs8 = s & 7;
    s16x8 o;
    #pragma unroll
    for (int u = 0; u < 8; u++) {
      int p = bs8*8 + u;
      int key = (p & ~12) | ((p & 4) << 1) | ((p & 8) >> 1);  // swap bits 2,3
      o[u] = vt[key][d];
    }
    *(s16x8*)&Vt[((size_t)(bh*HS + d))*SEQ + s0 + bs8*8] = o;
  }
}

// ---------- flash attention, 32x32x16 MFMA, fixed-max softmax ----------
// QBLK=64 (2 waves x 32 q-rows), KVBLK=128. P never leaves registers.
__global__ __launch_bounds__(128) void k_attn(
    const bf16* __restrict__ qkv, const bf16* __restrict__ Vt, bf16* __restrict__ av)
{
  __shared__ __align__(16) short Ks[128*64];   // [key][d],  8 chunks/row, ^(row&7)
  __shared__ __align__(16) short Vs[64*128];   // [d][pos], 16 chunks/row, ^(row&15)
  int t = threadIdx.x;
  int lane = t & 63, w = t >> 6;
  int ql = lane & 31, hi = lane >> 5;
  int nwg = gridDim.x*gridDim.y;
  int swzid = xcd_swz(blockIdx.y*gridDim.x + blockIdx.x, nwg);
  int qt = swzid & 31, bh = swzid >> 5;
  int b = bh >> 4, h = bh & 15;

  // Q fragments (B-operand): lane needs Q[q=ql][d = ks*16 + hi*8 + 0..7]
  const bf16* qrow = qkv + (size_t)(b*SEQ + qt*64 + w*32 + ql)*NQKV + h*HS;
  s16x8 qf[4];
  #pragma unroll
  for (int ks = 0; ks < 4; ks++)
    qf[ks] = *(const s16x8*)&qrow[ks*16 + hi*8];

  float psum = 0.f;
  f32x16 oacc0 = {}, oacc1 = {};

  const bf16* kbase = qkv + (size_t)(b*SEQ)*NQKV + HIDDEN + h*HS;
  const bf16* vbase = Vt + (size_t)(bh*HS)*SEQ;

  const float SC2 = 0.125f*1.44269504f;   // (1/sqrt(64)) * log2(e)
  const float CB  = -12.f*1.44269504f;    // -M*log2(e), fixed softmax max M=12

  for (int kv = 0; kv < SEQ; kv += 128) {
    __syncthreads();
    // stage K tile [128 keys][64 d]; source pre-swizzled, LDS dest linear
    #pragma unroll
    for (int c = 0; c < 8; c++) {
      int s = c*128 + t, r = s >> 3, bd = s & 7, bs = bd ^ (r & 7);
      GLOAD_LDS(&kbase[(size_t)(kv + r)*NQKV + bs*8], &Ks[s*8]);
    }
    // stage V^T tile [64 d][128 pos]; 16-chunk swizzle ^(d&15)
    #pragma unroll
    for (int c = 0; c < 8; c++) {
      int s = c*128 + t, d = s >> 4, bd = s & 15, bs = bd ^ (d & 15);
      GLOAD_LDS(&vbase[(size_t)d*SEQ + kv + bs*8], &Vs[s*8]);
    }
    __syncthreads();

    #pragma unroll
    for (int kb = 0; kb < 4; kb++) {          // 32-key blocks
      // S^T = K*Q^T : 4 MFMA over d=64; lane holds S[key a(r,hi)][q=ql]
      f32x16 sf = {};
      __builtin_amdgcn_s_setprio(1);
      #pragma unroll
      for (int ks = 0; ks < 4; ks++) {
        int row = kb*32 + ql;
        int ch = (ks*2 + hi) ^ (row & 7);
        s16x8 a = *(const s16x8*)&Ks[(row*8 + ch)*8];
        sf = __builtin_amdgcn_mfma_f32_32x32x16_bf16(a, qf[ks], sf, 0, 0, 0);
      }
      __builtin_amdgcn_s_setprio(0);

      // p = exp2(s*SC2 + CB); pack pairs -> PV A-fragments (slot j = r&7)
      unsigned pkw[8];
      #pragma unroll
      for (int i = 0; i < 8; i++) {
        float p0 = __builtin_amdgcn_exp2f(__builtin_fmaf(sf[2*i],   SC2, CB));
        float p1 = __builtin_amdgcn_exp2f(__builtin_fmaf(sf[2*i+1], SC2, CB));
        psum += p0 + p1;
        pkw[i] = cvt_pk_bf16(p0, p1);
      }

      // PV: 4 MFMA (2 key-sub-blocks x 2 d-blocks)
      __builtin_amdgcn_s_setprio(1);
      #pragma unroll
      for (int kq = 0; kq < 2; kq++) {
        union { unsigned u[4]; s16x8 v; } pu;
        pu.u[0] = pkw[kq*4]; pu.u[1] = pkw[kq*4+1];
        pu.u[2] = pkw[kq*4+2]; pu.u[3] = pkw[kq*4+3];
        s16x8 pa = pu.v;
        {
          int row = ql, ch = (kb*4 + kq*2 + hi) ^ (row & 15);
          s16x8 vb = *(const s16x8*)&Vs[(row*16 + ch)*8];
          oacc0 = __builtin_amdgcn_mfma_f32_32x32x16_bf16(pa, vb, oacc0, 0, 0, 0);
        }
        {
          int row = 32 + ql, ch = (kb*4 + kq*2 + hi) ^ (row & 15);
          s16x8 vb = *(const s16x8*)&Vs[(row*16 + ch)*8];
          oacc1 = __builtin_amdgcn_mfma_f32_32x32x16_bf16(pa, vb, oacc1, 0, 0, 0);
        }
      }
      __builtin_amdgcn_s_setprio(0);
    }
  }

  // psum: lane covers keys with its hi; partner lane^32 has the other half
  psum += __shfl_xor(psum, 32);
  float linv = 1.f/psum;

  // write O: reg r -> q-row (r&3)+8*(r>>2)+4*hi, d-col = dblk*32 + ql
  #pragma unroll
  for (int r = 0; r < 16; r++) {
    int qr = (r & 3) + 8*(r >> 2) + 4*hi;
    float lr = __shfl(linv, qr);
    int row = b*SEQ + qt*64 + w*32 + qr;
    bf16* orow = av + (size_t)row*HIDDEN + h*HS;
    orow[ql]      = __float2bfloat16(oacc0[r]*lr);
    orow[32 + ql] = __float2bfloat16(oacc1[r]*lr);
  }
}

extern "C" void kernel_launch(void* const* d_in, const int* in_sizes, int n_in,
                              void* d_out, int out_size, void* d_ws, size_t ws_size,
                              hipStream_t stream) {
  const float* x    = (const float*)d_in[0];
  const float* Wqkv = (const float*)d_in[1];
  const float* bqkv = (const float*)d_in[2];
  const float* Wo   = (const float*)d_in[3];
  const float* bo   = (const float*)d_in[4];

  char* ws = (char*)d_ws;
  bf16* xb    = (bf16*)(ws);                 // 8 MB  (dead after gemm1; reused as av)
  bf16* av    = xb;
  bf16* WqkvT = (bf16*)(ws + (8  << 20));    // 6 MB
  bf16* WoT   = (bf16*)(ws + (14 << 20));    // 2 MB
  bf16* qkv   = (bf16*)(ws + (16 << 20));    // 24 MB
  bf16* Vt    = (bf16*)(ws + (40 << 20));    // 8 MB   (total 48 MB)

  k_cvt_x<<<dim3(MTOT*HIDDEN/8/256), 256, 0, stream>>>(x, (short*)xb, MTOT*HIDDEN/8);
  k_cvt_wT<<<dim3(NQKV/64, HIDDEN/64), 256, 0, stream>>>(Wqkv, WqkvT, HIDDEN, NQKV);
  k_cvt_wT<<<dim3(HIDDEN/64, HIDDEN/64), 256, 0, stream>>>(Wo, WoT, HIDDEN, HIDDEN);
  k_gemm<1><<<dim3(NQKV/128, MTOT/128), 256, 0, stream>>>(xb, WqkvT, bqkv, qkv, MTOT, NQKV, HIDDEN);
  k_repack_v<<<dim3(SEQ/64, BATCH*NHEAD), 256, 0, stream>>>(qkv, Vt);
  k_attn<<<dim3(SEQ/64, BATCH*NHEAD), 128, 0, stream>>>(qkv, Vt, av);
  k_gemm<0><<<dim3(HIDDEN/128, MTOT/128), 256, 0, stream>>>(av, WoT, bo, d_out, MTOT, HIDDEN, HIDDEN);
}

// Round 5
// 118.618 us; speedup vs baseline: 1.0525x; 1.0525x over previous
//
#include <hip/hip_runtime.h>
#include <hip/hip_bf16.h>
#include <stdint.h>

#define HIDDEN 1024
#define NHEAD  16
#define HS     64
#define BATCH  2
#define SEQ    2048
#define MTOT   (BATCH*SEQ)
#define NQKV   (3*HIDDEN)

typedef __hip_bfloat16 bf16;
typedef __attribute__((ext_vector_type(8))) short s16x8;
typedef __attribute__((ext_vector_type(4))) float f32x4;
typedef __attribute__((ext_vector_type(16))) float f32x16;

__device__ __forceinline__ short f2bf(float f) {
  bf16 h = __float2bfloat16(f);
  return *reinterpret_cast<short*>(&h);
}

__device__ __forceinline__ unsigned cvt_pk_bf16(float lo, float hi) {
  unsigned r;
  asm("v_cvt_pk_bf16_f32 %0, %1, %2" : "=v"(r) : "v"(lo), "v"(hi));
  return r;
}

// LDS chunk-swizzle, 8 chunks (16B each) per row: chunk blk lives at blk^(row&7).
__device__ __forceinline__ int swz(int row, int blk) {
  return (row*8 + (blk ^ (row & 7)))*8;
}

#define GLOAD_LDS(gp, lp) \
  __builtin_amdgcn_global_load_lds((const __attribute__((address_space(1))) void*)(gp), \
                                   (__attribute__((address_space(3))) void*)(lp), 16, 0, 0)

// bijective XCD-chunk swizzle; requires nwg % 8 == 0 (true for all our grids)
__device__ __forceinline__ int xcd_swz(int orig, int nwg) {
  return (orig & 7)*(nwg >> 3) + (orig >> 3);
}

// ---------------- convert x (fp32 -> bf16), 8 elems/thread ----------------
__global__ void k_cvt_x(const float* __restrict__ x, short* __restrict__ xb, int n8) {
  int i = blockIdx.x*256 + threadIdx.x;
  if (i >= n8) return;
  const f32x4* xv = (const f32x4*)x;
  f32x4 a = xv[2*i], b = xv[2*i+1];
  s16x8 o = { f2bf(a[0]), f2bf(a[1]), f2bf(a[2]), f2bf(a[3]),
              f2bf(b[0]), f2bf(b[1]), f2bf(b[2]), f2bf(b[3]) };
  *(s16x8*)&xb[i*8] = o;
}

// ------------- transpose-convert W[K][N] fp32 -> WT[N][K] bf16 -------------
__global__ void k_cvt_wT(const float* __restrict__ W, bf16* __restrict__ WT, int K, int N) {
  __shared__ __align__(16) float tile[64][65];
  int n0 = blockIdx.x*64, k0 = blockIdx.y*64;
  int t = threadIdx.x;
  #pragma unroll
  for (int c = 0; c < 4; c++) {
    int s = c*256 + t;
    int r = s >> 4;
    int cc = s & 15;
    f32x4 v = *(const f32x4*)&W[(size_t)(k0 + r)*N + n0 + cc*4];
    tile[r][cc*4+0] = v[0]; tile[r][cc*4+1] = v[1];
    tile[r][cc*4+2] = v[2]; tile[r][cc*4+3] = v[3];
  }
  __syncthreads();
  #pragma unroll
  for (int c = 0; c < 2; c++) {
    int s = c*256 + t;
    int r = s >> 3;
    int cc = s & 7;
    s16x8 o;
    #pragma unroll
    for (int u = 0; u < 8; u++) o[u] = f2bf(tile[cc*8+u][r]);
    *(s16x8*)&WT[(size_t)(n0 + r)*K + k0 + cc*8] = o;
  }
}

// -------- GEMM: C[M][N] = A[M][K](bf16) * BT[N][K]^T(bf16) + bias --------
template<int OUT_BF16>
__global__ __launch_bounds__(256) void k_gemm(
    const bf16* __restrict__ A, const bf16* __restrict__ BT,
    const float* __restrict__ bias, void* __restrict__ Cout,
    int M, int N, int K)
{
  __shared__ __align__(16) short Asl[128*64];
  __shared__ __align__(16) short Bsl[128*64];
  int t = threadIdx.x;
  int lane = t & 63, w = t >> 6;
  int q = lane & 15, g = lane >> 4;
  int nwg = gridDim.x*gridDim.y;
  int swzid = xcd_swz(blockIdx.y*gridDim.x + blockIdx.x, nwg);
  int bx = swzid % gridDim.x, by = swzid / gridDim.x;
  int row0 = by*128, col0 = bx*128;
  int wr = (w >> 1)*64, wc = (w & 1)*64;

  f32x4 acc[4][4] = {};

  for (int kt = 0; kt < K; kt += 64) {
    __syncthreads();
    #pragma unroll
    for (int c = 0; c < 4; c++) {
      int s = c*256 + t, r = s >> 3, bd = s & 7, bs = bd ^ (r & 7);
      GLOAD_LDS(&A[(size_t)(row0 + r)*K + kt + bs*8], &Asl[s*8]);
      GLOAD_LDS(&BT[(size_t)(col0 + r)*K + kt + bs*8], &Bsl[s*8]);
    }
    __syncthreads();
    #pragma unroll
    for (int kk = 0; kk < 2; kk++) {
      s16x8 af[4], bfr[4];
      #pragma unroll
      for (int i = 0; i < 4; i++) {
        af[i]  = *(const s16x8*)&Asl[swz(wr + i*16 + q, kk*4 + g)];
        bfr[i] = *(const s16x8*)&Bsl[swz(wc + i*16 + q, kk*4 + g)];
      }
      __builtin_amdgcn_s_setprio(1);
      #pragma unroll
      for (int i = 0; i < 4; i++)
        #pragma unroll
        for (int j = 0; j < 4; j++)
          acc[i][j] = __builtin_amdgcn_mfma_f32_16x16x32_bf16(af[i], bfr[j], acc[i][j], 0, 0, 0);
      __builtin_amdgcn_s_setprio(0);
    }
  }
  #pragma unroll
  for (int i = 0; i < 4; i++) {
    #pragma unroll
    for (int j = 0; j < 4; j++) {
      int col = col0 + wc + j*16 + q;
      float bv = bias[col];
      int rowb = row0 + wr + i*16 + g*4;
      #pragma unroll
      for (int r = 0; r < 4; r++) {
        float v = acc[i][j][r] + bv;
        if (OUT_BF16)
          ((bf16*)Cout)[(size_t)(rowb + r)*N + col] = __float2bfloat16(v);
        else
          ((float*)Cout)[(size_t)(rowb + r)*N + col] = v;
      }
    }
  }
}

// ------- repack V with PV key-permutation baked into column order -------
// For 32x32x16 swapped-QK^T: S^T reg r of lane (q,hi) holds key
// a = (r&3)+8*(r>>2)+4*hi; PV A-frag slot needs pos = (r>>3)*16+hi*8+(r&7).
// a = pos with bits 2<->3 swapped. So Vt[.][s0+p] = V[s0 + bitswap23(p)][.].
__global__ void k_repack_v(const bf16* __restrict__ qkv, bf16* __restrict__ Vt) {
  int s0 = blockIdx.x*64;
  int bh = blockIdx.y;
  int b = bh >> 4, h = bh & 15;
  __shared__ __align__(16) short vt[64][68];
  int t = threadIdx.x;
  #pragma unroll
  for (int c = 0; c < 2; c++) {
    int s = c*256 + t, r = s >> 3, bd = s & 7;
    s16x8 v = *(const s16x8*)&qkv[(size_t)(b*SEQ + s0 + r)*NQKV + 2*HIDDEN + h*HS + bd*8];
    #pragma unroll
    for (int u = 0; u < 8; u++) vt[r][bd*8+u] = v[u];
  }
  __syncthreads();
  #pragma unroll
  for (int c = 0; c < 2; c++) {
    int s = c*256 + t, d = s >> 3, bs8 = s & 7;
    s16x8 o;
    #pragma unroll
    for (int u = 0; u < 8; u++) {
      int p = bs8*8 + u;
      int key = (p & ~12) | ((p & 4) << 1) | ((p & 8) >> 1);  // swap bits 2,3
      o[u] = vt[key][d];
    }
    *(s16x8*)&Vt[((size_t)(bh*HS + d))*SEQ + s0 + bs8*8] = o;
  }
}

// ---------- flash attention, 32x32x16 MFMA, fixed-max softmax ----------
// QBLK=128 (4 waves x 32 q-rows), KVBLK=128, double-buffered LDS (64 KB),
// one barrier per tile: stage(next) issued BEFORE compute(cur), drained by
// __syncthreads()'s implicit vmcnt(0). P never leaves registers.
struct AttnState {
  float psum;
  f32x16 oacc0, oacc1;
};

__device__ __forceinline__ void attn_stage(
    const bf16* __restrict__ kbase, const bf16* __restrict__ vbase,
    int kv, int t, short* Ks, short* Vs)
{
  #pragma unroll
  for (int c = 0; c < 4; c++) {          // K tile [128 keys][64 d]
    int s = c*256 + t, r = s >> 3, bd = s & 7, bs = bd ^ (r & 7);
    GLOAD_LDS(&kbase[(size_t)(kv + r)*NQKV + bs*8], &Ks[s*8]);
  }
  #pragma unroll
  for (int c = 0; c < 4; c++) {          // V^T tile [64 d][128 pos], ^(d&15)
    int s = c*256 + t, d = s >> 4, bd = s & 15, bs = bd ^ (d & 15);
    GLOAD_LDS(&vbase[(size_t)d*SEQ + kv + bs*8], &Vs[s*8]);
  }
}

__device__ __forceinline__ void attn_compute(
    const short* Ks, const short* Vs, const s16x8* qf,
    int ql, int hi, AttnState& st)
{
  const float SC2 = 0.125f*1.44269504f;   // (1/sqrt(64)) * log2(e)
  const float CB  = -12.f*1.44269504f;    // -M*log2(e), fixed softmax max M=12
  #pragma unroll
  for (int kb = 0; kb < 4; kb++) {        // 32-key blocks
    f32x16 sf = {};
    __builtin_amdgcn_s_setprio(1);
    #pragma unroll
    for (int ks = 0; ks < 4; ks++) {
      int row = kb*32 + ql;
      int ch = (ks*2 + hi) ^ (row & 7);
      s16x8 a = *(const s16x8*)&Ks[(row*8 + ch)*8];
      sf = __builtin_amdgcn_mfma_f32_32x32x16_bf16(a, qf[ks], sf, 0, 0, 0);
    }
    __builtin_amdgcn_s_setprio(0);

    unsigned pkw[8];
    #pragma unroll
    for (int i = 0; i < 8; i++) {
      float p0 = __builtin_amdgcn_exp2f(__builtin_fmaf(sf[2*i],   SC2, CB));
      float p1 = __builtin_amdgcn_exp2f(__builtin_fmaf(sf[2*i+1], SC2, CB));
      st.psum += p0 + p1;
      pkw[i] = cvt_pk_bf16(p0, p1);
    }

    __builtin_amdgcn_s_setprio(1);
    #pragma unroll
    for (int kq = 0; kq < 2; kq++) {
      union { unsigned u[4]; s16x8 v; } pu;
      pu.u[0] = pkw[kq*4]; pu.u[1] = pkw[kq*4+1];
      pu.u[2] = pkw[kq*4+2]; pu.u[3] = pkw[kq*4+3];
      s16x8 pa = pu.v;
      {
        int row = ql, ch = (kb*4 + kq*2 + hi) ^ (row & 15);
        s16x8 vb = *(const s16x8*)&Vs[(row*16 + ch)*8];
        st.oacc0 = __builtin_amdgcn_mfma_f32_32x32x16_bf16(pa, vb, st.oacc0, 0, 0, 0);
      }
      {
        int row = 32 + ql, ch = (kb*4 + kq*2 + hi) ^ (row & 15);
        s16x8 vb = *(const s16x8*)&Vs[(row*16 + ch)*8];
        st.oacc1 = __builtin_amdgcn_mfma_f32_32x32x16_bf16(pa, vb, st.oacc1, 0, 0, 0);
      }
    }
    __builtin_amdgcn_s_setprio(0);
  }
}

__global__ __launch_bounds__(256) void k_attn(
    const bf16* __restrict__ qkv, const bf16* __restrict__ Vt, bf16* __restrict__ av)
{
  __shared__ __align__(16) short Ks0[128*64], Ks1[128*64];  // 16 KB each
  __shared__ __align__(16) short Vs0[64*128], Vs1[64*128];  // 16 KB each
  int t = threadIdx.x;
  int lane = t & 63, w = t >> 6;
  int ql = lane & 31, hi = lane >> 5;
  int nwg = gridDim.x*gridDim.y;
  int swzid = xcd_swz(blockIdx.y*gridDim.x + blockIdx.x, nwg);
  int qt = swzid & 15, bh = swzid >> 4;
  int b = bh >> 4, h = bh & 15;

  // Q fragments (B-operand): lane needs Q[q=ql][d = ks*16 + hi*8 + 0..7]
  const bf16* qrow = qkv + (size_t)(b*SEQ + qt*128 + w*32 + ql)*NQKV + h*HS;
  s16x8 qf[4];
  #pragma unroll
  for (int ks = 0; ks < 4; ks++)
    qf[ks] = *(const s16x8*)&qrow[ks*16 + hi*8];

  AttnState st;
  st.psum = 0.f;
  st.oacc0 = (f32x16){}; st.oacc1 = (f32x16){};

  const bf16* kbase = qkv + (size_t)(b*SEQ)*NQKV + HIDDEN + h*HS;
  const bf16* vbase = Vt + (size_t)(bh*HS)*SEQ;

  attn_stage(kbase, vbase, 0, t, Ks0, Vs0);
  __syncthreads();

  #pragma unroll 1
  for (int tt = 0; tt < SEQ/128; tt += 2) {
    int kv = tt*128;
    if (kv + 128 < SEQ) attn_stage(kbase, vbase, kv + 128, t, Ks1, Vs1);
    attn_compute(Ks0, Vs0, qf, ql, hi, st);
    __syncthreads();
    if (kv + 256 < SEQ) attn_stage(kbase, vbase, kv + 256, t, Ks0, Vs0);
    attn_compute(Ks1, Vs1, qf, ql, hi, st);
    __syncthreads();
  }

  // psum: lane covers keys with its hi; partner lane^32 has the other half
  float psum = st.psum + __shfl_xor(st.psum, 32);
  float linv = 1.f/psum;

  // write O: reg r -> q-row (r&3)+8*(r>>2)+4*hi, d-col = dblk*32 + ql
  #pragma unroll
  for (int r = 0; r < 16; r++) {
    int qr = (r & 3) + 8*(r >> 2) + 4*hi;
    float lr = __shfl(linv, qr);
    int row = b*SEQ + qt*128 + w*32 + qr;
    bf16* orow = av + (size_t)row*HIDDEN + h*HS;
    orow[ql]      = __float2bfloat16(st.oacc0[r]*lr);
    orow[32 + ql] = __float2bfloat16(st.oacc1[r]*lr);
  }
}

extern "C" void kernel_launch(void* const* d_in, const int* in_sizes, int n_in,
                              void* d_out, int out_size, void* d_ws, size_t ws_size,
                              hipStream_t stream) {
  const float* x    = (const float*)d_in[0];
  const float* Wqkv = (const float*)d_in[1];
  const float* bqkv = (const float*)d_in[2];
  const float* Wo   = (const float*)d_in[3];
  const float* bo   = (const float*)d_in[4];

  char* ws = (char*)d_ws;
  bf16* xb    = (bf16*)(ws);                 // 8 MB  (dead after gemm1; reused as av)
  bf16* av    = xb;
  bf16* WqkvT = (bf16*)(ws + (8  << 20));    // 6 MB
  bf16* WoT   = (bf16*)(ws + (14 << 20));    // 2 MB
  bf16* qkv   = (bf16*)(ws + (16 << 20));    // 24 MB
  bf16* Vt    = (bf16*)(ws + (40 << 20));    // 8 MB   (total 48 MB)

  k_cvt_x<<<dim3(MTOT*HIDDEN/8/256), 256, 0, stream>>>(x, (short*)xb, MTOT*HIDDEN/8);
  k_cvt_wT<<<dim3(NQKV/64, HIDDEN/64), 256, 0, stream>>>(Wqkv, WqkvT, HIDDEN, NQKV);
  k_cvt_wT<<<dim3(HIDDEN/64, HIDDEN/64), 256, 0, stream>>>(Wo, WoT, HIDDEN, HIDDEN);
  k_gemm<1><<<dim3(NQKV/128, MTOT/128), 256, 0, stream>>>(xb, WqkvT, bqkv, qkv, MTOT, NQKV, HIDDEN);
  k_repack_v<<<dim3(SEQ/64, BATCH*NHEAD), 256, 0, stream>>>(qkv, Vt);
  k_attn<<<dim3(SEQ/128, BATCH*NHEAD), 256, 0, stream>>>(qkv, Vt, av);
  k_gemm<0><<<dim3(HIDDEN/128, MTOT/128), 256, 0, stream>>>(av, WoT, bo, d_out, MTOT, HIDDEN, HIDDEN);
}